// Round 3
// baseline (67.196 us; speedup 1.0000x reference)
//
#include <hip/hip_runtime.h>

#define BUFF 10

constexpr int B = 8, N = 4096, H = 2048, W = 2048;
constexpr int NPTS = B * N;
constexpr int KW = 21;                        // max window dim (2*BUFF+1)
constexpr int KCELLS = KW * KW;               // 441 padded cells
constexpr int KITER = (KCELLS + 63) / 64;     // 7 unrolled iterations

// Binning: 128 buckets = (image b: 3 bits) x (py>>7 row-band: 4 bits).
// One bucket's pixel footprint = 128 rows x 2048 cols x 4B x 2 arrays ~= 2 MB -> fits one XCD's 4 MB L2.
constexpr int NBUCK = 128;
constexpr int CAP = 512;                      // bucket capacity (mean 256, sigma ~15.5 -> +16 sigma safe)
constexpr int PTS_PER_BLOCK = 4;              // 4 waves/block, 1 point/wave
constexpr int GRPS = CAP / PTS_PER_BLOCK;     // 128 slot-groups per bucket
constexpr size_t WS_NEEDED = 512 + (size_t)NBUCK * CAP * 4;  // counters + slot arrays

__device__ __forceinline__ void window_of_point(const float* __restrict__ pts, int idx,
                                                int& tx, int& ty, int& ww, int& hh, int& total) {
    // replicate JAX f32 arithmetic exactly: p=(v+1)/2; px=trunc(p*W)
    const float vx = pts[2 * idx + 0];
    const float vy = pts[2 * idx + 1];
    const int px = (int)(((vx + 1.0f) / 2.0f) * (float)W);
    const int py = (int)(((vy + 1.0f) / 2.0f) * (float)H);
    tx = min(max(px - BUFF, 0), W - 1);
    ty = min(max(py - BUFF, 0), H - 1);
    const int bx = min(max(px + BUFF, 0), W - 1);
    const int by = min(max(py + BUFF, 0), H - 1);
    ww = bx - tx;                             // in [9, 20]
    hh = by - ty;
    total = ww * hh;                          // actual window area (<= 400, >= ~81)
}

__device__ __forceinline__ float gather_score(const int* __restrict__ gtb, const int* __restrict__ psb,
                                              int tx, int ty, int ww, int hh, int total, int lane) {
    int acc = 0;
    #pragma unroll
    for (int k = 0; k < KITER; ++k) {
        const int i = lane + k * 64;          // 0..447 over padded 21x21 grid
        const int r = i / KW;                 // const divide -> magic mul
        const int c = i - r * KW;
        const bool valid = (i < KCELLS) & (r < hh) & (c < ww);
        const int rr = min(r, hh - 1);
        const int cc = min(c, ww - 1);
        const int off = (ty + rr) * W + (tx + cc);
        const int g = gtb[off];
        const int p = psb[off];
        acc += (valid && (g == p)) ? 1 : 0;
    }
    #pragma unroll
    for (int o = 32; o > 0; o >>= 1) acc += __shfl_down(acc, o, 64);
    return fminf(fmaxf(fabsf((float)acc / (float)total), 0.0f), 1.0f);
}

// ---- binned path ----

__global__ __launch_bounds__(256) void bin_points(const float* __restrict__ pts,
                                                  int* __restrict__ cnt, int* __restrict__ slots) {
    const int idx = blockIdx.x * 256 + threadIdx.x;
    if (idx >= NPTS) return;
    const int b = idx >> 12;
    const float vy = pts[2 * idx + 1];
    int py = (int)(((vy + 1.0f) / 2.0f) * (float)H);
    py = min(max(py, 0), H - 1);
    const int key = (b << 4) | (py >> 7);
    const int pos = atomicAdd(&cnt[key], 1);
    if (pos < CAP) slots[key * CAP + pos] = idx;
}

__global__ __launch_bounds__(256) void score_windows_binned(
    const float* __restrict__ pts, const int* __restrict__ gt, const int* __restrict__ ps,
    const int* __restrict__ cnt, const int* __restrict__ slots, float* __restrict__ out)
{
    // blockIdx -> (xcd, slot_grp, bucket_within_xcd): consecutive blocks on one XCD
    // sweep all slots of one bucket before moving to the next bucket (temporal clustering).
    const int bid = blockIdx.x;
    const int xcd = bid & 7;                  // round-robin XCD assignment heuristic
    const int t = bid >> 3;
    const int slot_grp = t & (GRPS - 1);      // 0..127
    const int bwx = t >> 7;                   // 0..15
    const int bucket = bwx * 8 + xcd;         // bucket % 8 == xcd

    const int wid = threadIdx.x >> 6;
    const int lane = threadIdx.x & 63;
    const int slot = slot_grp * PTS_PER_BLOCK + wid;

    const int nc = min(cnt[bucket], CAP);
    if (slot >= nc) return;                   // wave-uniform early exit
    const int idx = slots[bucket * CAP + slot];

    int tx, ty, ww, hh, total;
    window_of_point(pts, idx, tx, ty, ww, hh, total);
    const int b = idx >> 12;
    const int* __restrict__ gtb = gt + (size_t)b * (size_t)(H * W);
    const int* __restrict__ psb = ps + (size_t)b * (size_t)(H * W);

    const float sgt = gather_score(gtb, psb, tx, ty, ww, hh, total, lane);
    if (lane == 0) out[1 + idx] = sgt;
}

// fixed-order loss over scores_gt (independent of gather processing order -> deterministic)
__global__ __launch_bounds__(1024) void loss_from_scores(const float* __restrict__ scores,
                                                         float* __restrict__ out) {
    __shared__ float sdata[1024];
    float s = 0.0f;
    for (int i = threadIdx.x; i < NPTS; i += 1024) {
        const float d = scores[i] - out[1 + i];
        s += d * d;
    }
    sdata[threadIdx.x] = s;
    __syncthreads();
    #pragma unroll
    for (int k = 512; k > 0; k >>= 1) {
        if (threadIdx.x < k) sdata[threadIdx.x] += sdata[threadIdx.x + k];
        __syncthreads();
    }
    if (threadIdx.x == 0) out[0] = sdata[0] / (float)NPTS;
}

// ---- fallback path (round-2 kernel, used if ws too small) ----

__global__ __launch_bounds__(256) void score_windows_flat(
    const float* __restrict__ pts, const int* __restrict__ gt, const int* __restrict__ ps,
    float* __restrict__ out)
{
    const int tid = blockIdx.x * blockDim.x + threadIdx.x;
    const int idx = tid >> 6;
    const int lane = threadIdx.x & 63;
    int tx, ty, ww, hh, total;
    window_of_point(pts, idx, tx, ty, ww, hh, total);
    const int b = idx >> 12;
    const int* __restrict__ gtb = gt + (size_t)b * (size_t)(H * W);
    const int* __restrict__ psb = ps + (size_t)b * (size_t)(H * W);
    const float sgt = gather_score(gtb, psb, tx, ty, ww, hh, total, lane);
    if (lane == 0) out[1 + idx] = sgt;
}

extern "C" void kernel_launch(void* const* d_in, const int* in_sizes, int n_in,
                              void* d_out, int out_size, void* d_ws, size_t ws_size,
                              hipStream_t stream) {
    const float* scores = (const float*)d_in[0];   // [B,N]
    const float* points = (const float*)d_in[1];   // [B,N,2]
    const int*   gt     = (const int*)d_in[2];     // [B,1,H,W]
    const int*   ps     = (const int*)d_in[3];     // [B,H,W]
    float* out = (float*)d_out;                    // [1 + B*N]

    if (ws_size >= WS_NEEDED) {
        int* cnt   = (int*)d_ws;                   // 128 counters
        int* slots = (int*)((char*)d_ws + 512);    // 128 x 512 point indices
        hipMemsetAsync(cnt, 0, 512, stream);
        bin_points<<<(NPTS + 255) / 256, 256, 0, stream>>>(points, cnt, slots);
        score_windows_binned<<<NBUCK * GRPS, 256, 0, stream>>>(points, gt, ps, cnt, slots, out);
    } else {
        score_windows_flat<<<NPTS / PTS_PER_BLOCK, 256, 0, stream>>>(points, gt, ps, out);
    }
    loss_from_scores<<<1, 1024, 0, stream>>>(scores, out);
}

// Round 4
// 45.870 us; speedup vs baseline: 1.4649x; 1.4649x over previous
//
#include <hip/hip_runtime.h>

#define BUFF 10

constexpr int B = 8, N = 4096, H = 2048, W = 2048;
constexpr int NPTS = B * N;
constexpr int WAVES_PER_BLOCK = 4;            // 256 threads, 1 point/wave
constexpr int NBLOCKS = NPTS / WAVES_PER_BLOCK;  // 8192
constexpr int MAXD = 2 * BUFF;                // max window rows/cols = 20
constexpr int WORDS = 6;                      // int4 words/row: 24 cols >= ww(<=20) + (tx&3)(<=3)
constexpr int CELLS = MAXD * WORDS;           // 120 int4 cells over padded grid
constexpr int ITERS = (CELLS + 63) / 64;      // 2 unrolled iterations

__global__ __launch_bounds__(256) void score_windows(
    const float* __restrict__ scores, const float* __restrict__ points,
    const int* __restrict__ gt, const int* __restrict__ ps,
    float* __restrict__ out, float* __restrict__ partial)
{
    const int tid  = blockIdx.x * blockDim.x + threadIdx.x;
    const int idx  = tid >> 6;            // one wave per point
    const int lane = threadIdx.x & 63;
    const int wid  = threadIdx.x >> 6;

    const int b = idx >> 12;              // idx / N

    // replicate JAX f32 arithmetic exactly: p=(v+1)/2; px=trunc(p*W)
    const float vx = points[2 * idx + 0];
    const float vy = points[2 * idx + 1];
    const int px = (int)(((vx + 1.0f) / 2.0f) * (float)W);
    const int py = (int)(((vy + 1.0f) / 2.0f) * (float)H);

    const int tx = min(max(px - BUFF, 0), W - 1);
    const int ty = min(max(py - BUFF, 0), H - 1);
    const int bx = min(max(px + BUFF, 0), W - 1);
    const int by = min(max(py + BUFF, 0), H - 1);

    const int ww = bx - tx;               // in [10, 20]
    const int hh = by - ty;
    const int total = ww * hh;            // actual window area

    const int4* __restrict__ gt4 = reinterpret_cast<const int4*>(gt + (size_t)b * (size_t)(H * W));
    const int4* __restrict__ ps4 = reinterpret_cast<const int4*>(ps + (size_t)b * (size_t)(H * W));

    const int a   = tx & ~3;              // int4-aligned col start
    const int txe = tx + ww;              // exclusive col end

    // Padded 20x6 grid of int4 words; 4 dwordx4 loads/wave total (vs 14 dword).
    int acc = 0;
    #pragma unroll
    for (int k = 0; k < ITERS; ++k) {
        const int i = lane + k * 64;              // 0..127 (>= 120 cells)
        const int r = i / WORDS;                  // const divide -> magic mul
        const int c = i - r * WORDS;
        const int ucol = a + 4 * c;               // unclamped col of elem 0
        const int col4 = min(ucol, W - 4);        // clamp: stay inside row/array
        const int rr = min(r, hh - 1);            // safe row for addressing
        const int w4 = ((ty + rr) * W + col4) >> 2;
        const int4 g = gt4[w4];
        const int4 p = ps4[w4];
        // mask with UNCLAMPED cols: clamped words have ucol+e >= W > any window col
        const bool rv = (r < hh);
        acc += (rv && (ucol + 0 >= tx) && (ucol + 0 < txe) && (g.x == p.x)) ? 1 : 0;
        acc += (rv && (ucol + 1 >= tx) && (ucol + 1 < txe) && (g.y == p.y)) ? 1 : 0;
        acc += (rv && (ucol + 2 >= tx) && (ucol + 2 < txe) && (g.z == p.z)) ? 1 : 0;
        acc += (rv && (ucol + 3 >= tx) && (ucol + 3 < txe) && (g.w == p.w)) ? 1 : 0;
    }

    // 64-lane wave reduction
    #pragma unroll
    for (int o = 32; o > 0; o >>= 1) acc += __shfl_down(acc, o, 64);

    __shared__ float wsum[WAVES_PER_BLOCK];
    if (lane == 0) {
        const float sgt = fminf(fmaxf(fabsf((float)acc / (float)total), 0.0f), 1.0f);
        out[1 + idx] = sgt;
        const float d = scores[idx] - sgt;
        wsum[wid] = d * d;
    }
    __syncthreads();
    if (threadIdx.x == 0) {
        partial[blockIdx.x] = wsum[0] + wsum[1] + wsum[2] + wsum[3];
    }
}

__global__ __launch_bounds__(1024) void loss_reduce(
    const float* __restrict__ partial, float* __restrict__ out, int nparts)
{
    __shared__ float sdata[1024];
    float s = 0.0f;
    for (int i = threadIdx.x; i < nparts; i += 1024) s += partial[i];  // fixed order
    sdata[threadIdx.x] = s;
    __syncthreads();
    #pragma unroll
    for (int k = 512; k > 0; k >>= 1) {
        if (threadIdx.x < k) sdata[threadIdx.x] += sdata[threadIdx.x + k];
        __syncthreads();
    }
    if (threadIdx.x == 0) out[0] = sdata[0] / (float)NPTS;
}

extern "C" void kernel_launch(void* const* d_in, const int* in_sizes, int n_in,
                              void* d_out, int out_size, void* d_ws, size_t ws_size,
                              hipStream_t stream) {
    const float* scores = (const float*)d_in[0];   // [B,N]
    const float* points = (const float*)d_in[1];   // [B,N,2]
    const int*   gt     = (const int*)d_in[2];     // [B,1,H,W]
    const int*   ps     = (const int*)d_in[3];     // [B,H,W]
    float* out     = (float*)d_out;                // [1 + B*N]
    float* partial = (float*)d_ws;                 // NBLOCKS floats (32 KB)

    score_windows<<<NBLOCKS, 256, 0, stream>>>(scores, points, gt, ps, out, partial);
    loss_reduce<<<1, 1024, 0, stream>>>(partial, out, NBLOCKS);
}